// Round 2
// baseline (879.612 us; speedup 1.0000x reference)
//
#include <hip/hip_runtime.h>
#include <cstdint>
#include <cstddef>

// Problem constants (fixed by reference)
#define N_SEQ 64
#define T_LEN 256
#define VOCAB 32000
#define EDIM  256
#define KS    128          // hidden states
#define KK    16384        // KS*KS
#define MROWS 16384        // padded (t,n) rows for GEMM (real: 255*64 = 16320)
#define MREAL 16320

typedef short  short8  __attribute__((ext_vector_type(8)));
typedef float  floatx4 __attribute__((ext_vector_type(4)));

static __device__ __forceinline__ unsigned short f2bf(float f) {
  unsigned u = __float_as_uint(f);
  u += 0x7fffu + ((u >> 16) & 1u);          // RNE
  return (unsigned short)(u >> 16);
}

static __device__ __forceinline__ void gl_lds16(const void* gptr, void* lptr) {
  // async global->LDS, 16B per lane; LDS dest = wave-uniform base + lane*16
  __builtin_amdgcn_global_load_lds(
      (const __attribute__((address_space(1))) void*)gptr,
      (__attribute__((address_space(3))) void*)lptr, 16, 0, 0);
}

// ---------------- start-distribution log_softmax -------------------------
__global__ __launch_bounds__(128) void k_prep(const float* sw, const float* sb, float* pre0) {
  __shared__ float vals[KS];
  __shared__ float MM, LS;
  int tid = threadIdx.x;
  float v = sw[tid] + sb[tid];
  vals[tid] = v;
  __syncthreads();
  if (tid == 0) { float m = vals[0]; for (int i = 1; i < KS; ++i) m = fmaxf(m, vals[i]); MM = m; }
  __syncthreads();
  float e = __expf(v - MM);
  vals[tid] = e;
  __syncthreads();
  if (tid == 0) { float s = 0.f; for (int i = 0; i < KS; ++i) s += vals[i]; LS = MM + __logf(s); }
  __syncthreads();
  pre0[tid] = v - LS;
}

// ---------------- trans_w fp32 -> bf16 (same [c][e] layout) --------------
__global__ __launch_bounds__(256) void k_transcvt(const float* tw, unsigned short* tb) {
  int idx = blockIdx.x * 256 + threadIdx.x;          // over float4 groups
  if (idx >= (KK * EDIM) / 4) return;
  float4 v = *(const float4*)&tw[(size_t)idx * 4];
  unsigned h0 = f2bf(v.x), h1 = f2bf(v.y), h2 = f2bf(v.z), h3 = f2bf(v.w);
  uint2 o; o.x = h0 | (h1 << 16); o.y = h2 | (h3 << 16);
  *(uint2*)&tb[(size_t)idx * 4] = o;
}

// ---------------- gather token embeddings -> bf16 rows m = t*64+n --------
__global__ __launch_bounds__(256) void k_embed(const int* x, const float* ew, unsigned short* exb) {
  int m = blockIdx.x, e = threadIdx.x;
  int t = m >> 6, n = m & 63;
  float v = 0.f;
  if (m < MREAL) { int tok = x[n * T_LEN + t]; v = ew[(size_t)tok * EDIM + e]; }
  exb[(size_t)m * EDIM + e] = f2bf(v);
}

// ---------------- emission logits C[k][v] = ecl[k] . emit_w[v] -----------
__global__ __launch_bounds__(256) void k_emitlogits(const float* ecl, const float* emw, float* C) {
  int v0 = blockIdx.x * 64, k0 = blockIdx.y * 64;
  int tid = threadIdx.x;
  __shared__ alignas(16) float At[64 * 17];
  __shared__ alignas(16) float Bt[64 * 17];
  int tx = tid & 15, ty = tid >> 4;
  int r = tid >> 2, q = tid & 3;
  float acc[4][4] = {};
  for (int d0 = 0; d0 < KS; d0 += 16) {
    float4 av = *(const float4*)&ecl[(size_t)(k0 + r) * KS + d0 + q * 4];
    float4 bv = *(const float4*)&emw[(size_t)(v0 + r) * KS + d0 + q * 4];
    __syncthreads();
    At[r * 17 + q * 4 + 0] = av.x; At[r * 17 + q * 4 + 1] = av.y;
    At[r * 17 + q * 4 + 2] = av.z; At[r * 17 + q * 4 + 3] = av.w;
    Bt[r * 17 + q * 4 + 0] = bv.x; Bt[r * 17 + q * 4 + 1] = bv.y;
    Bt[r * 17 + q * 4 + 2] = bv.z; Bt[r * 17 + q * 4 + 3] = bv.w;
    __syncthreads();
    #pragma unroll
    for (int dd = 0; dd < 16; ++dd) {
      float a[4], b[4];
      #pragma unroll
      for (int i = 0; i < 4; ++i) a[i] = At[(ty * 4 + i) * 17 + dd];
      #pragma unroll
      for (int i = 0; i < 4; ++i) b[i] = Bt[(tx * 4 + i) * 17 + dd];
      #pragma unroll
      for (int i = 0; i < 4; ++i)
        #pragma unroll
        for (int jj = 0; jj < 4; ++jj) acc[i][jj] += a[i] * b[jj];
    }
  }
  #pragma unroll
  for (int i = 0; i < 4; ++i) {
    float4 o; o.x = acc[i][0]; o.y = acc[i][1]; o.z = acc[i][2]; o.w = acc[i][3];
    *(float4*)&C[(size_t)(k0 + ty * 4 + i) * VOCAB + v0 + tx * 4] = o;
  }
}

// ---------------- per-cluster lse over vocab -----------------------------
__global__ __launch_bounds__(256) void k_lsec(const float* C, float* lseC) {
  int k = blockIdx.x, tid = threadIdx.x;
  __shared__ float sm[4], ss[4];
  const float* row = C + (size_t)k * VOCAB;
  float m = -1e30f;
  for (int v = tid; v < VOCAB; v += 256) m = fmaxf(m, row[v]);
  #pragma unroll
  for (int s = 1; s < 64; s <<= 1) m = fmaxf(m, __shfl_xor(m, s));
  if ((tid & 63) == 0) sm[tid >> 6] = m;
  __syncthreads();
  m = fmaxf(fmaxf(sm[0], sm[1]), fmaxf(sm[2], sm[3]));
  float sum = 0.f;
  for (int v = tid; v < VOCAB; v += 256) sum += __expf(row[v] - m);
  #pragma unroll
  for (int s = 1; s < 64; s <<= 1) sum += __shfl_xor(sum, s);
  if ((tid & 63) == 0) ss[tid >> 6] = sum;
  __syncthreads();
  if (tid == 0) lseC[k] = m + __logf(ss[0] + ss[1] + ss[2] + ss[3]);
}

// ---------------- gather emission log-probs emis[n][t][k] ----------------
__global__ __launch_bounds__(128) void k_emis(const int* x, const float* C, const float* lseC, float* emis) {
  int t = blockIdx.x + 1;          // 1..255
  int n = blockIdx.y;
  int k = threadIdx.x;
  int w = x[n * T_LEN + t];
  emis[(size_t)((n << 8) + t) * KS + k] = C[(size_t)k * VOCAB + w] - lseC[k];
}

// ---- big GEMM chunk: S[mloc][c] = exp(exb[m_base+mloc].trb[c]) fp8 ------
// also srow[m][by] = sum_c-in-block exp(.) == per-k_prev softmax denom
__global__ __launch_bounds__(256) void k_gemm(const unsigned short* exb, const unsigned short* trb,
                                              unsigned char* S, float* srow, int m_base) {
  int bx = blockIdx.x, by = blockIdx.y;
  int tid = threadIdx.x, wv = tid >> 6, ln = tid & 63;
  int wc = wv & 1, wm = wv >> 1;
  __shared__ alignas(16) unsigned short As[128 * 64];
  __shared__ alignas(16) unsigned short Bs[128 * 64];
  __shared__ float sred[2][128];
  floatx4 acc[4][4] = {};                 // [fc][fm]; Cᵀ: rows=c, cols=m
  int m0 = m_base + bx * 128;             // global row base
  int c0 = by * 128;
  int lr = ln & 15, lk = (ln >> 4) * 8;
  for (int k0 = 0; k0 < EDIM; k0 += 64) {
    #pragma unroll
    for (int r = 0; r < 4; ++r) {
      int chunk = (wv * 4 + r) * 64 + ln;   // 16B chunk id in 16KB tile
      int row = chunk >> 3, c8 = chunk & 7;
      gl_lds16(&exb[(size_t)(m0 + row) * EDIM + k0 + c8 * 8], &As[(wv * 4 + r) * 512]);
      gl_lds16(&trb[(size_t)(c0 + row) * EDIM + k0 + c8 * 8], &Bs[(wv * 4 + r) * 512]);
    }
    __syncthreads();
    #pragma unroll
    for (int kk = 0; kk < 64; kk += 32) {
      short8 af[4], bf[4];
      #pragma unroll
      for (int f = 0; f < 4; ++f)
        af[f] = *(const short8*)&As[(wm * 64 + f * 16 + lr) * 64 + kk + lk];
      #pragma unroll
      for (int f = 0; f < 4; ++f)
        bf[f] = *(const short8*)&Bs[(wc * 64 + f * 16 + lr) * 64 + kk + lk];
      #pragma unroll
      for (int fc = 0; fc < 4; ++fc)
        #pragma unroll
        for (int fm = 0; fm < 4; ++fm)
          acc[fc][fm] = __builtin_amdgcn_mfma_f32_16x16x32_bf16(bf[fc], af[fm], acc[fc][fm], 0, 0, 0);
    }
    __syncthreads();
  }
  // epilogue: exp, fp8 pack (4 consecutive c per lane), row-sums per m
  float psum[4] = {0.f, 0.f, 0.f, 0.f};
  int g = ln >> 4;
  #pragma unroll
  for (int fc = 0; fc < 4; ++fc) {
    #pragma unroll
    for (int fm = 0; fm < 4; ++fm) {
      floatx4 a = acc[fc][fm];
      float e0 = __expf(a[0]), e1 = __expf(a[1]), e2 = __expf(a[2]), e3 = __expf(a[3]);
      int p = __builtin_amdgcn_cvt_pk_fp8_f32(e0, e1, 0, 0);
      p = __builtin_amdgcn_cvt_pk_fp8_f32(e2, e3, p, 1);
      int mloc = bx * 128 + wm * 64 + fm * 16 + lr;   // chunk-local row
      int c = c0 + wc * 64 + fc * 16 + g * 4;
      *(int*)&S[(size_t)mloc * KK + c] = p;
      psum[fm] += e0 + e1 + e2 + e3;
    }
  }
  #pragma unroll
  for (int fm = 0; fm < 4; ++fm) {
    psum[fm] += __shfl_xor(psum[fm], 16);
    psum[fm] += __shfl_xor(psum[fm], 32);
  }
  if (ln < 16) {
    #pragma unroll
    for (int fm = 0; fm < 4; ++fm) sred[wc][wm * 64 + fm * 16 + ln] = psum[fm];
  }
  __syncthreads();
  if (tid < 128) srow[(size_t)(m0 + tid) * KS + by] = sred[0][tid] + sred[1][tid];
}

// ---------------- sequential forward scan chunk, one block per sequence --
__global__ __launch_bounds__(1024) void k_scan(const unsigned char* S, const float* srow,
                                               const float* emis, const float* pre0,
                                               float* alphaG, float* nll, int t0, int tc) {
  int n = blockIdx.x, tid = threadIdx.x;
  __shared__ float pre[KS];
  __shared__ float u[KS];
  __shared__ float part[8 * KS];
  __shared__ alignas(16) uint4 Sb4[KK / 16];
  unsigned char* Sb = (unsigned char*)Sb4;
  __shared__ float red[1];
  int t1 = t0 + tc;
  if (tid < KS) pre[tid] = (t0 == 1) ? pre0[tid] : alphaG[n * KS + tid];
  uint4 nxt = *(const uint4*)&S[(size_t)n * KK + tid * 16];     // local row for step t0
  __syncthreads();
  int j = tid & 127, gi = tid >> 7;
  for (int t = t0; t < t1; ++t) {
    Sb4[tid] = nxt;                                             // stage step t
    if (t + 1 < t1) nxt = *(const uint4*)&S[(size_t)((t + 1 - t0) * 64 + n) * KK + tid * 16];
    if (tid < 64) {
      float m2 = fmaxf(pre[tid], pre[tid + 64]);
      #pragma unroll
      for (int s = 1; s < 64; s <<= 1) m2 = fmaxf(m2, __shfl_xor(m2, s));
      if (tid == 0) red[0] = m2;
    }
    __syncthreads();                                            // Sb + max ready
    float M = red[0];
    if (tid < KS) u[tid] = __expf(pre[tid] - M) / srow[(size_t)((t - 1) * 64 + n) * KS + tid];
    __syncthreads();                                            // u ready
    float a = 0.f;
    int ib = gi * 16;
    #pragma unroll
    for (int ii = 0; ii < 16; ++ii) {
      int iv = ib + ii;
      a += u[iv] * __builtin_amdgcn_cvt_f32_fp8((int)Sb[iv * 128 + j], 0);
    }
    part[gi * KS + j] = a;
    __syncthreads();                                            // partials; Sb reads done
    if (tid < KS) {
      float c = 0.f;
      #pragma unroll
      for (int g2 = 0; g2 < 8; ++g2) c += part[g2 * KS + tid];
      pre[tid] = M + __logf(c) + emis[(size_t)((n << 8) + t) * KS + tid];
    }
    __syncthreads();                                            // pre ready
  }
  if (tid < KS) alphaG[n * KS + tid] = pre[tid];
  if (t1 == T_LEN && tid < 64) {
    float m2 = fmaxf(pre[tid], pre[tid + 64]);
    #pragma unroll
    for (int s = 1; s < 64; s <<= 1) m2 = fmaxf(m2, __shfl_xor(m2, s));
    float e = __expf(pre[tid] - m2) + __expf(pre[tid + 64] - m2);
    #pragma unroll
    for (int s = 1; s < 64; s <<= 1) e += __shfl_xor(e, s);
    if (tid == 0) nll[n] = m2 + __logf(e);
  }
}

// ---------------- final: out = -mean(nll) --------------------------------
__global__ __launch_bounds__(64) void k_final(const float* nll, float* out) {
  int tid = threadIdx.x;
  float v = nll[tid];
  #pragma unroll
  for (int s = 1; s < 64; s <<= 1) v += __shfl_xor(v, s);
  if (tid == 0) out[0] = -v / 64.0f;
}

extern "C" void kernel_launch(void* const* d_in, const int* in_sizes, int n_in,
                              void* d_out, int out_size, void* d_ws, size_t ws_size,
                              hipStream_t stream) {
  const int*   x       = (const int*)d_in[0];
  const float* embed_w = (const float*)d_in[1];
  const float* trans_w = (const float*)d_in[2];
  const float* start_w = (const float*)d_in[3];
  const float* start_b = (const float*)d_in[4];
  const float* ecl     = (const float*)d_in[5];
  const float* emw     = (const float*)d_in[6];

  char* w = (char*)d_ws;
  size_t off = 0;
  auto alloc = [&](size_t bytes) -> char* {
    char* p = w + off;
    off = (off + bytes + 255) & ~(size_t)255;
    return p;
  };
  float*          pre0   = (float*)alloc(KS * 4);
  float*          lseC   = (float*)alloc(KS * 4);
  float*          nll    = (float*)alloc(N_SEQ * 4);
  float*          alphaG = (float*)alloc((size_t)N_SEQ * KS * 4);
  unsigned short* trb    = (unsigned short*)alloc((size_t)KK * EDIM * 2);     // 8.39 MB
  unsigned short* exb    = (unsigned short*)alloc((size_t)MROWS * EDIM * 2);  // 8.39 MB
  float*          emis   = (float*)alloc((size_t)N_SEQ * T_LEN * KS * 4);     // 8.39 MB
  float*          srow   = (float*)alloc((size_t)MROWS * KS * 4);             // 8.39 MB
  // chunk region: holds fp8 S chunks; also aliases transient C (emission
  // logits, dead before first k_gemm). avail = everything that remains.
  char* region = w + off;
  size_t avail = (ws_size > off) ? (ws_size - off) : 0;
  float*         C = (float*)region;              // 128*32000*4 = 16.38 MB
  unsigned char* S = (unsigned char*)region;

  // pick largest even chunk Tc (cap 64) with (Tc+1)*64 rows * 16KB <= avail
  int Tc = 2;
  for (int c = 2; c <= 64; c += 2)
    if (((size_t)(c + 1) << 20) <= avail) Tc = c;

  hipLaunchKernelGGL(k_prep,       dim3(1),        dim3(128), 0, stream, start_w, start_b, pre0);
  hipLaunchKernelGGL(k_transcvt,   dim3(4096),     dim3(256), 0, stream, trans_w, trb);
  hipLaunchKernelGGL(k_embed,      dim3(16384),    dim3(256), 0, stream, x, embed_w, exb);
  hipLaunchKernelGGL(k_emitlogits, dim3(500, 2),   dim3(256), 0, stream, ecl, emw, C);
  hipLaunchKernelGGL(k_lsec,       dim3(128),      dim3(256), 0, stream, C, lseC);
  hipLaunchKernelGGL(k_emis,       dim3(255, 64),  dim3(128), 0, stream, x, C, lseC, emis);

  int t0 = 1;
  while (t0 < T_LEN) {
    int tc = T_LEN - t0; if (tc > Tc) tc = Tc;
    int m_base = (t0 - 1) * 64;
    int gx = (tc * 64 + 127) / 128;
    hipLaunchKernelGGL(k_gemm, dim3(gx, 128), dim3(256),  0, stream, exb, trb, S, srow, m_base);
    hipLaunchKernelGGL(k_scan, dim3(64),      dim3(1024), 0, stream, S, srow, emis, pre0, alphaG, nll, t0, tc);
    t0 += tc;
  }
  hipLaunchKernelGGL(k_final, dim3(1), dim3(64), 0, stream, nll, (float*)d_out);
}

// Round 3
// 735.512 us; speedup vs baseline: 1.1959x; 1.1959x over previous
//
#include <hip/hip_runtime.h>
#include <cstdint>
#include <cstddef>

// Problem constants (fixed by reference)
#define N_SEQ 64
#define T_LEN 256
#define VOCAB 32000
#define EDIM  256
#define KS    128          // hidden states
#define KK    16384        // KS*KS
#define MROWS 16384        // padded (t,n) rows for GEMM (real: 255*64 = 16320)
#define MREAL 16320

typedef short  short8  __attribute__((ext_vector_type(8)));
typedef float  floatx4 __attribute__((ext_vector_type(4)));

static __device__ __forceinline__ unsigned short f2bf(float f) {
  unsigned u = __float_as_uint(f);
  u += 0x7fffu + ((u >> 16) & 1u);          // RNE
  return (unsigned short)(u >> 16);
}

static __device__ __forceinline__ void gl_lds16(const void* gptr, void* lptr) {
  // async global->LDS, 16B per lane; LDS dest = wave-uniform base + lane*16
  __builtin_amdgcn_global_load_lds(
      (const __attribute__((address_space(1))) void*)gptr,
      (__attribute__((address_space(3))) void*)lptr, 16, 0, 0);
}

// ---------------- start-distribution log_softmax -------------------------
__global__ __launch_bounds__(128) void k_prep(const float* sw, const float* sb, float* pre0) {
  __shared__ float vals[KS];
  __shared__ float MM, LS;
  int tid = threadIdx.x;
  float v = sw[tid] + sb[tid];
  vals[tid] = v;
  __syncthreads();
  if (tid == 0) { float m = vals[0]; for (int i = 1; i < KS; ++i) m = fmaxf(m, vals[i]); MM = m; }
  __syncthreads();
  float e = __expf(v - MM);
  vals[tid] = e;
  __syncthreads();
  if (tid == 0) { float s = 0.f; for (int i = 0; i < KS; ++i) s += vals[i]; LS = MM + __logf(s); }
  __syncthreads();
  pre0[tid] = v - LS;
}

// ---------------- trans_w fp32 -> bf16 (same [c][e] layout) --------------
__global__ __launch_bounds__(256) void k_transcvt(const float* tw, unsigned short* tb) {
  int idx = blockIdx.x * 256 + threadIdx.x;          // over float4 groups
  if (idx >= (KK * EDIM) / 4) return;
  float4 v = *(const float4*)&tw[(size_t)idx * 4];
  unsigned h0 = f2bf(v.x), h1 = f2bf(v.y), h2 = f2bf(v.z), h3 = f2bf(v.w);
  uint2 o; o.x = h0 | (h1 << 16); o.y = h2 | (h3 << 16);
  *(uint2*)&tb[(size_t)idx * 4] = o;
}

// ---------------- gather token embeddings -> bf16 rows m = t*64+n --------
__global__ __launch_bounds__(256) void k_embed(const int* x, const float* ew, unsigned short* exb) {
  int m = blockIdx.x, e = threadIdx.x;
  int t = m >> 6, n = m & 63;
  float v = 0.f;
  if (m < MREAL) { int tok = x[n * T_LEN + t]; v = ew[(size_t)tok * EDIM + e]; }
  exb[(size_t)m * EDIM + e] = f2bf(v);
}

// ---------------- emission logits C[k][v] = ecl[k] . emit_w[v] -----------
__global__ __launch_bounds__(256) void k_emitlogits(const float* ecl, const float* emw, float* C) {
  int v0 = blockIdx.x * 64, k0 = blockIdx.y * 64;
  int tid = threadIdx.x;
  __shared__ alignas(16) float At[64 * 17];
  __shared__ alignas(16) float Bt[64 * 17];
  int tx = tid & 15, ty = tid >> 4;
  int r = tid >> 2, q = tid & 3;
  float acc[4][4] = {};
  for (int d0 = 0; d0 < KS; d0 += 16) {
    float4 av = *(const float4*)&ecl[(size_t)(k0 + r) * KS + d0 + q * 4];
    float4 bv = *(const float4*)&emw[(size_t)(v0 + r) * KS + d0 + q * 4];
    __syncthreads();
    At[r * 17 + q * 4 + 0] = av.x; At[r * 17 + q * 4 + 1] = av.y;
    At[r * 17 + q * 4 + 2] = av.z; At[r * 17 + q * 4 + 3] = av.w;
    Bt[r * 17 + q * 4 + 0] = bv.x; Bt[r * 17 + q * 4 + 1] = bv.y;
    Bt[r * 17 + q * 4 + 2] = bv.z; Bt[r * 17 + q * 4 + 3] = bv.w;
    __syncthreads();
    #pragma unroll
    for (int dd = 0; dd < 16; ++dd) {
      float a[4], b[4];
      #pragma unroll
      for (int i = 0; i < 4; ++i) a[i] = At[(ty * 4 + i) * 17 + dd];
      #pragma unroll
      for (int i = 0; i < 4; ++i) b[i] = Bt[(tx * 4 + i) * 17 + dd];
      #pragma unroll
      for (int i = 0; i < 4; ++i)
        #pragma unroll
        for (int jj = 0; jj < 4; ++jj) acc[i][jj] += a[i] * b[jj];
    }
  }
  #pragma unroll
  for (int i = 0; i < 4; ++i) {
    float4 o; o.x = acc[i][0]; o.y = acc[i][1]; o.z = acc[i][2]; o.w = acc[i][3];
    *(float4*)&C[(size_t)(k0 + ty * 4 + i) * VOCAB + v0 + tx * 4] = o;
  }
}

// ---------------- per-cluster lse over vocab -----------------------------
__global__ __launch_bounds__(256) void k_lsec(const float* C, float* lseC) {
  int k = blockIdx.x, tid = threadIdx.x;
  __shared__ float sm[4], ss[4];
  const float* row = C + (size_t)k * VOCAB;
  float m = -1e30f;
  for (int v = tid; v < VOCAB; v += 256) m = fmaxf(m, row[v]);
  #pragma unroll
  for (int s = 1; s < 64; s <<= 1) m = fmaxf(m, __shfl_xor(m, s));
  if ((tid & 63) == 0) sm[tid >> 6] = m;
  __syncthreads();
  m = fmaxf(fmaxf(sm[0], sm[1]), fmaxf(sm[2], sm[3]));
  float sum = 0.f;
  for (int v = tid; v < VOCAB; v += 256) sum += __expf(row[v] - m);
  #pragma unroll
  for (int s = 1; s < 64; s <<= 1) sum += __shfl_xor(sum, s);
  if ((tid & 63) == 0) ss[tid >> 6] = sum;
  __syncthreads();
  if (tid == 0) lseC[k] = m + __logf(ss[0] + ss[1] + ss[2] + ss[3]);
}

// ---------------- gather emission log-probs emis[n][t][k] ----------------
__global__ __launch_bounds__(128) void k_emis(const int* x, const float* C, const float* lseC, float* emis) {
  int t = blockIdx.x + 1;          // 1..255
  int n = blockIdx.y;
  int k = threadIdx.x;
  int w = x[n * T_LEN + t];
  emis[(size_t)((n << 8) + t) * KS + k] = C[(size_t)k * VOCAB + w] - lseC[k];
}

// ---- big GEMM chunk: S[mloc][c] = exp(exb[m_base+mloc].trb[c]) fp8 ------
// srowT[i][m] = sum_j exp(.)  (coalesced; transposed+rcp'd by k_srowt)
__global__ __launch_bounds__(256) void k_gemm(const unsigned short* exb, const unsigned short* trb,
                                              unsigned char* S, float* srowT, int m_base) {
  int bx = blockIdx.x, by = blockIdx.y;
  int tid = threadIdx.x, wv = tid >> 6, ln = tid & 63;
  int wc = wv & 1, wm = wv >> 1;
  __shared__ alignas(16) unsigned short As[128 * 64];
  __shared__ alignas(16) unsigned short Bs[128 * 64];
  __shared__ float sred[2][128];
  floatx4 acc[4][4] = {};                 // [fc][fm]; Cᵀ: rows=c, cols=m
  int m0 = m_base + bx * 128;             // global row base
  int c0 = by * 128;
  int lr = ln & 15, lk = (ln >> 4) * 8;
  for (int k0 = 0; k0 < EDIM; k0 += 64) {
    #pragma unroll
    for (int r = 0; r < 4; ++r) {
      int chunk = (wv * 4 + r) * 64 + ln;   // 16B chunk id in 16KB tile
      int row = chunk >> 3, c8 = chunk & 7;
      gl_lds16(&exb[(size_t)(m0 + row) * EDIM + k0 + c8 * 8], &As[(wv * 4 + r) * 512]);
      gl_lds16(&trb[(size_t)(c0 + row) * EDIM + k0 + c8 * 8], &Bs[(wv * 4 + r) * 512]);
    }
    __syncthreads();
    #pragma unroll
    for (int kk = 0; kk < 64; kk += 32) {
      short8 af[4], bf[4];
      #pragma unroll
      for (int f = 0; f < 4; ++f)
        af[f] = *(const short8*)&As[(wm * 64 + f * 16 + lr) * 64 + kk + lk];
      #pragma unroll
      for (int f = 0; f < 4; ++f)
        bf[f] = *(const short8*)&Bs[(wc * 64 + f * 16 + lr) * 64 + kk + lk];
      #pragma unroll
      for (int fc = 0; fc < 4; ++fc)
        #pragma unroll
        for (int fm = 0; fm < 4; ++fm)
          acc[fc][fm] = __builtin_amdgcn_mfma_f32_16x16x32_bf16(bf[fc], af[fm], acc[fc][fm], 0, 0, 0);
    }
    __syncthreads();
  }
  // epilogue: exp, fp8 pack into LDS tile (XOR bank swizzle), row-sums
  unsigned char* Ts = (unsigned char*)As;  // reuse 16 KB, dead after last barrier
  float psum[4] = {0.f, 0.f, 0.f, 0.f};
  int g = ln >> 4;
  #pragma unroll
  for (int fc = 0; fc < 4; ++fc) {
    #pragma unroll
    for (int fm = 0; fm < 4; ++fm) {
      floatx4 a = acc[fc][fm];
      float e0 = __expf(a[0]), e1 = __expf(a[1]), e2 = __expf(a[2]), e3 = __expf(a[3]);
      int p = __builtin_amdgcn_cvt_pk_fp8_f32(e0, e1, 0, 0);
      p = __builtin_amdgcn_cvt_pk_fp8_f32(e2, e3, p, 1);
      int mloc = wm * 64 + fm * 16 + lr;
      int cl = wc * 64 + fc * 16 + g * 4;
      *(int*)&Ts[mloc * 128 + (cl ^ ((mloc & 7) << 4))] = p;
      psum[fm] += e0 + e1 + e2 + e3;
    }
  }
  #pragma unroll
  for (int fm = 0; fm < 4; ++fm) {
    psum[fm] += __shfl_xor(psum[fm], 16);
    psum[fm] += __shfl_xor(psum[fm], 32);
  }
  if (ln < 16) {
    #pragma unroll
    for (int fm = 0; fm < 4; ++fm) sred[wc][wm * 64 + fm * 16 + ln] = psum[fm];
  }
  __syncthreads();                          // Ts + sred ready
  #pragma unroll
  for (int r = 0; r < 4; ++r) {
    int seg = r * 256 + tid;                // 1024 x 16B segments
    int mloc = seg >> 3, s = seg & 7;
    uint4 v = *(const uint4*)&Ts[mloc * 128 + ((s * 16) ^ ((mloc & 7) << 4))];
    *(uint4*)&S[(size_t)(bx * 128 + mloc) * KK + by * 128 + s * 16] = v;
  }
  if (tid < 128) srowT[(size_t)by * MROWS + m0 + tid] = sred[0][tid] + sred[1][tid];
}

// ------------- srowT[i][m] -> srowR[m][i] = 1/srowT (32x32 tiles) --------
__global__ __launch_bounds__(256) void k_srowt(const float* srowT, float* srowR, int m_base) {
  __shared__ float tile[32][33];
  int mt = blockIdx.x * 32 + m_base;
  int it = blockIdx.y * 32;
  int row = threadIdx.x >> 5, col = threadIdx.x & 31;
  #pragma unroll
  for (int r = 0; r < 4; ++r)
    tile[row + r * 8][col] = srowT[(size_t)(it + row + r * 8) * MROWS + mt + col];
  __syncthreads();
  #pragma unroll
  for (int r = 0; r < 4; ++r)
    srowR[(size_t)(mt + row + r * 8) * KS + it + col] = 1.0f / tile[col][row + r * 8];
}

// ---------------- sequential forward scan chunk, one block per sequence --
// 2 barriers/step; M = alpha[state 0] maintained thread-locally (no shuffles)
__global__ __launch_bounds__(1024) void k_scan(const unsigned char* S, const float* srowR,
                                               const float* emis, const float* pre0,
                                               float* alphaG, float* nll, int t0, int tc) {
  int n = blockIdx.x, tid = threadIdx.x;
  int j = tid & 127, gi = tid >> 7;
  __shared__ float u[KS];
  __shared__ float part[8 * 132];
  __shared__ alignas(16) uint4 Sb4[KK / 16];
  unsigned char* Sb = (unsigned char*)Sb4;
  int t1 = t0 + tc;
  float pre_j, M;
  if (t0 == 1) { pre_j = pre0[j]; M = pre0[0]; }
  else         { pre_j = alphaG[n * KS + j]; M = alphaG[n * KS]; }
  float rs  = srowR[(size_t)((t0 - 1) * 64 + n) * KS + j];
  float em  = emis[(size_t)((n << 8) + t0) * KS + j];
  float em0 = emis[(size_t)((n << 8) + t0) * KS];
  uint4 nxt = *(const uint4*)&S[(size_t)n * KK + tid * 16];
  for (int t = t0; t < t1; ++t) {
    // A: stage S(t), publish u(t); prefetch everything for t+1
    Sb4[tid] = nxt;
    float us = __expf(pre_j - M) * rs;
    if (gi == 0) u[j] = us;
    if (t + 1 < t1) nxt = *(const uint4*)&S[(size_t)((t + 1 - t0) * 64 + n) * KK + tid * 16];
    float rsn = 0.f, emn = 0.f, emn0 = 0.f;
    if (t + 1 < T_LEN) {
      rsn  = srowR[(size_t)(t * 64 + n) * KS + j];
      emn  = emis[(size_t)((n << 8) + t + 1) * KS + j];
      emn0 = emis[(size_t)((n << 8) + t + 1) * KS];
    }
    __syncthreads();                           // u + Sb ready
    // B: matvec partials
    float a = 0.f;
    int ib = gi * 16;
    #pragma unroll
    for (int ii = 0; ii < 16; ++ii)
      a += u[ib + ii] * __builtin_amdgcn_cvt_f32_fp8((int)Sb[(ib + ii) * 128 + j], 0);
    part[gi * 132 + j] = a;
    __syncthreads();                           // partials ready
    // C: reduce; every thread tracks M = alpha[0] redundantly (broadcast reads)
    float c = 0.f, c0 = 0.f;
    #pragma unroll
    for (int g = 0; g < 8; ++g) { c += part[g * 132 + j]; c0 += part[g * 132]; }
    pre_j = M + __logf(c) + em;
    M     = M + __logf(c0) + em0;
    rs = rsn; em = emn; em0 = emn0;
  }
  __syncthreads();
  if (gi == 0) alphaG[n * KS + j] = pre_j;
  if (t1 == T_LEN) {
    float e = __expf(pre_j - M);               // 8 redundant copies per state
    #pragma unroll
    for (int s = 1; s < 64; s <<= 1) e += __shfl_xor(e, s);
    if ((tid & 63) == 0) part[tid >> 6] = e;
    __syncthreads();
    if (tid == 0) {
      float s = 0.f;
      for (int wv = 0; wv < 16; ++wv) s += part[wv];
      nll[n] = M + __logf(s * 0.125f);         // divide out the 8x redundancy
    }
  }
}

// ---------------- final: out = -mean(nll) --------------------------------
__global__ __launch_bounds__(64) void k_final(const float* nll, float* out) {
  int tid = threadIdx.x;
  float v = nll[tid];
  #pragma unroll
  for (int s = 1; s < 64; s <<= 1) v += __shfl_xor(v, s);
  if (tid == 0) out[0] = -v / 64.0f;
}

extern "C" void kernel_launch(void* const* d_in, const int* in_sizes, int n_in,
                              void* d_out, int out_size, void* d_ws, size_t ws_size,
                              hipStream_t stream) {
  const int*   x       = (const int*)d_in[0];
  const float* embed_w = (const float*)d_in[1];
  const float* trans_w = (const float*)d_in[2];
  const float* start_w = (const float*)d_in[3];
  const float* start_b = (const float*)d_in[4];
  const float* ecl     = (const float*)d_in[5];
  const float* emw     = (const float*)d_in[6];

  char* w = (char*)d_ws;
  size_t off = 0;
  auto alloc = [&](size_t bytes) -> char* {
    char* p = w + off;
    off = (off + bytes + 255) & ~(size_t)255;
    return p;
  };
  float*          pre0   = (float*)alloc(KS * 4);
  float*          lseC   = (float*)alloc(KS * 4);
  float*          nll    = (float*)alloc(N_SEQ * 4);
  float*          alphaG = (float*)alloc((size_t)N_SEQ * KS * 4);
  unsigned short* trb    = (unsigned short*)alloc((size_t)KK * EDIM * 2);     // 8.39 MB
  unsigned short* exb    = (unsigned short*)alloc((size_t)MROWS * EDIM * 2);  // 8.39 MB
  float*          emis   = (float*)alloc((size_t)N_SEQ * T_LEN * KS * 4);     // 8.39 MB
  float*          srowT  = (float*)alloc((size_t)MROWS * KS * 4);             // 8.39 MB
  float*          srowR  = (float*)alloc((size_t)MROWS * KS * 4);             // 8.39 MB
  // chunk region: holds fp8 S chunks; also aliases transient C (emission
  // logits, dead before first k_gemm). avail = everything that remains.
  char* region = w + off;
  size_t avail = (ws_size > off) ? (ws_size - off) : 0;
  float*         C = (float*)region;              // 128*32000*4 = 16.38 MB
  unsigned char* S = (unsigned char*)region;

  // pick largest even chunk Tc (cap 64) with (Tc+1)*64 rows * 16KB <= avail
  int Tc = 2;
  for (int c = 2; c <= 64; c += 2)
    if (((size_t)(c + 1) << 20) <= avail) Tc = c;

  hipLaunchKernelGGL(k_prep,       dim3(1),        dim3(128), 0, stream, start_w, start_b, pre0);
  hipLaunchKernelGGL(k_transcvt,   dim3(4096),     dim3(256), 0, stream, trans_w, trb);
  hipLaunchKernelGGL(k_embed,      dim3(16384),    dim3(256), 0, stream, x, embed_w, exb);
  hipLaunchKernelGGL(k_emitlogits, dim3(500, 2),   dim3(256), 0, stream, ecl, emw, C);
  hipLaunchKernelGGL(k_lsec,       dim3(128),      dim3(256), 0, stream, C, lseC);
  hipLaunchKernelGGL(k_emis,       dim3(255, 64),  dim3(128), 0, stream, x, C, lseC, emis);

  int t0 = 1;
  while (t0 < T_LEN) {
    int tc = T_LEN - t0; if (tc > Tc) tc = Tc;
    int m_base = (t0 - 1) * 64;
    int gx = (tc * 64 + 127) / 128;
    hipLaunchKernelGGL(k_gemm,  dim3(gx, 128),      dim3(256),  0, stream, exb, trb, S, srowT, m_base);
    hipLaunchKernelGGL(k_srowt, dim3(gx * 4, 4),    dim3(256),  0, stream, srowT, srowR, m_base);
    hipLaunchKernelGGL(k_scan,  dim3(64),           dim3(1024), 0, stream, S, srowR, emis, pre0, alphaG, nll, t0, tc);
    t0 += tc;
  }
  hipLaunchKernelGGL(k_final, dim3(1), dim3(64), 0, stream, nll, (float*)d_out);
}